// Round 5
// baseline (1401.556 us; speedup 1.0000x reference)
//
#include <hip/hip_runtime.h>
#include <hip/hip_bf16.h>
#include <stdint.h>

#define OUT_F 8192
#define IN_F  8192
#define RANK  16
#define M_TOT 1024   // B*S
#define BM 128
#define BN 128
#define BK 64
#define NK (IN_F / BK)   // 128
#define SCB (IN_F / 32)  // 256 scale blocks per weight row

typedef __bf16 bf16x8 __attribute__((ext_vector_type(8)));
typedef float  f32x4  __attribute__((ext_vector_type(4)));

// round-half-up f32->bf16 pack of two floats into one uint32 (lo in low half)
static __device__ __forceinline__ uint32_t pack_bf16(float lo, float hi) {
    uint32_t a = __builtin_bit_cast(uint32_t, lo);
    uint32_t b = __builtin_bit_cast(uint32_t, hi);
    return ((a + 0x8000u) >> 16) | ((b + 0x8000u) & 0xffff0000u);
}

// ---------------------------------------------------------------------------
// Kernel 1 (prep, proven round-3): t zero + x fp32->bf16 + q int32->u8 narrow.
// ---------------------------------------------------------------------------
__global__ __launch_bounds__(256) void prep_kernel(
    const float* __restrict__ x, const int* __restrict__ q,
    uint2* __restrict__ xb2, uint32_t* __restrict__ qu32,
    float* __restrict__ t)
{
    const int gid = blockIdx.x * 256 + threadIdx.x;   // 0..524287 (2048 blocks)
    if (gid < M_TOT * RANK) t[gid] = 0.f;

    const float4* x4 = (const float4*)x;
#pragma unroll
    for (int j = 0; j < 4; ++j) {
        const int i = gid + j * 524288;
        const float4 v = x4[i];
        uint2 p;
        p.x = pack_bf16(v.x, v.y);
        p.y = pack_bf16(v.z, v.w);
        xb2[i] = p;
    }

    const int4* q4 = (const int4*)q;
#pragma unroll 8
    for (int k = 0; k < 32; ++k) {
        const size_t i = (size_t)gid + (size_t)k * 524288;
        const int4 a = q4[i];
        qu32[i] = (uint32_t)a.x | ((uint32_t)a.y << 8) |
                  ((uint32_t)a.z << 16) | ((uint32_t)a.w << 24);
    }
}

// ---------------------------------------------------------------------------
// Kernel 1C (legacy prep: x convert + t zero only).
// ---------------------------------------------------------------------------
__global__ __launch_bounds__(256) void convert_kernel(
    const float* __restrict__ x, uint2* __restrict__ xb2, float* __restrict__ t)
{
    const int tid = threadIdx.x, b = blockIdx.x;
    if (b < 64) t[b * 256 + tid] = 0.f;
    const float4* x4 = (const float4*)x;
    const int base = b * 256 + tid;
#pragma unroll
    for (int j = 0; j < 8; ++j) {
        const int i = base + j * 262144;       // 2M float4 total
        const float4 v = x4[i];
        uint2 p;
        p.x = pack_bf16(v.x, v.y);
        p.y = pack_bf16(v.z, v.w);
        xb2[i] = p;
    }
}

// ---------------------------------------------------------------------------
// Kernel 2: t = x @ lora_A^T via MFMA split-K + atomicAdd (reads xb bf16).
// ---------------------------------------------------------------------------
__global__ __launch_bounds__(256) void lora_t_kernel(
    const uint16_t* __restrict__ xb, const float* __restrict__ lora_A,
    float* __restrict__ t)
{
    const int b = blockIdx.x;           // 1024 blocks
    const int mt = b >> 6, ks = b & 63;
    const int tid = threadIdx.x, wave = tid >> 6, lane = tid & 63;
    const int fr = lane & 15, quad = lane >> 4;
    const int m = mt * 64 + wave * 16 + fr;
    const int k0 = ks * 128 + quad * 8;

    f32x4 acc = {0.f, 0.f, 0.f, 0.f};
    const uint16_t* xr = xb + (size_t)m * IN_F + k0;
    const float* ar = lora_A + (size_t)fr * IN_F + k0;

#pragma unroll
    for (int s = 0; s < 4; ++s) {
        const bf16x8 af = *(const bf16x8*)(xr + s * 32);
        const float4 a0 = *(const float4*)(ar + s * 32);
        const float4 a1 = *(const float4*)(ar + s * 32 + 4);
        bf16x8 bfr;
        uint32_t* bp = (uint32_t*)&bfr;
        bp[0] = pack_bf16(a0.x, a0.y); bp[1] = pack_bf16(a0.z, a0.w);
        bp[2] = pack_bf16(a1.x, a1.y); bp[3] = pack_bf16(a1.z, a1.w);
        acc = __builtin_amdgcn_mfma_f32_16x16x32_bf16(af, bfr, acc, 0, 0, 0);
    }
    const int mout = mt * 64 + wave * 16 + quad * 4;
#pragma unroll
    for (int r = 0; r < 4; ++r)
        atomicAdd(&t[(size_t)(mout + r) * RANK + fr], acc[r]);
}

// ---------------------------------------------------------------------------
// Kernel 3A (split-K u8 path): single-buffered 32 KB LDS (m97 structure:
// stage -> barrier -> compute -> barrier), split-K=2 -> 1024 blocks ->
// 4 blocks/CU, 16 waves/CU. Index math identical to the proven u8 kernel;
// only sync structure and K-range changed. LoRA contributes once (ks==0).
// ---------------------------------------------------------------------------
#define GEMM_STEP_S(KT, KTN, P)                                                \
    {                                                                          \
        _Pragma("unroll")                                                      \
        for (int i = 0; i < 4; ++i) {                                          \
            __builtin_amdgcn_global_load_lds(                                  \
                (const __attribute__((address_space(1))) uint32_t*)(xsrc + (size_t)(KT) * BK + (size_t)i * 8 * IN_F), \
                (__attribute__((address_space(3))) uint32_t*)(&xs[(wave * 32 + i * 8) * BK]), \
                16, 0, 0);                                                     \
        }                                                                      \
        _Pragma("unroll")                                                      \
        for (int j = 0; j < 8; ++j) {                                          \
            const float s = sc[P][j];                                          \
            const float c = -128.f * s;                                        \
            const uint32_t qq = qv[P][j];                                      \
            uint2 pk;                                                          \
            pk.x = pack_bf16(fmaf((float)(qq & 0xffu), s, c),                  \
                             fmaf((float)((qq >> 8) & 0xffu), s, c));          \
            pk.y = pack_bf16(fmaf((float)((qq >> 16) & 0xffu), s, c),          \
                             fmaf((float)(qq >> 24), s, c));                   \
            *(uint2*)(&wt[(qrow + 16 * j) * BK + wpos]) = pk;                  \
        }                                                                      \
        _Pragma("unroll")                                                      \
        for (int j = 0; j < 8; ++j) {                                          \
            const int row = qrow + 16 * j;                                     \
            qv[(P) ^ 1][j] = *(const uint32_t*)(qbase + (size_t)row * IN_F + (size_t)(KTN) * BK); \
            sc[(P) ^ 1][j] = scales[(size_t)(n0 + row) * SCB + (KTN) * 2 + qhi]; \
        }                                                                      \
        __syncthreads();  /* drains vmcnt0 (xs DMA + qv) and lgkm (wt writes) */ \
        _Pragma("unroll")                                                      \
        for (int kk = 0; kk < BK; kk += 32) {                                  \
            bf16x8 af[4], bfr[4];                                              \
            const int pp = (((kk >> 3) + quad) ^ (fr & 7)) * 8;                \
            _Pragma("unroll")                                                  \
            for (int i = 0; i < 4; ++i)                                        \
                af[i] = *(const bf16x8*)(&xs[(wm * 64 + i * 16 + fr) * BK + pp]); \
            _Pragma("unroll")                                                  \
            for (int j = 0; j < 4; ++j)                                        \
                bfr[j] = *(const bf16x8*)(&wt[(wn * 64 + j * 16 + fr) * BK + pp]); \
            _Pragma("unroll")                                                  \
            for (int i = 0; i < 4; ++i)                                        \
                _Pragma("unroll")                                              \
                for (int j = 0; j < 4; ++j)                                    \
                    acc[i][j] = __builtin_amdgcn_mfma_f32_16x16x32_bf16(af[i], bfr[j], acc[i][j], 0, 0, 0); \
        }                                                                      \
        __syncthreads();  /* compute done; LDS reusable */                     \
    }

__global__ __launch_bounds__(256, 4) void gemm_u8s_kernel(
    const uint16_t* __restrict__ xb,    // bf16 x  [1024][8192] (in ws)
    const uint8_t*  __restrict__ qu8,   // u8      [8192][8192] (in ws)
    const float*    __restrict__ scales,// fp32    [8192][256]
    const float*    __restrict__ t,     // fp32    [1024][16]   (in ws)
    const float*    __restrict__ loraB, // fp32    [8192][16]
    float*          __restrict__ part)  // fp32    [2][1024][8192] partials (ws)
{
    __shared__ __align__(16) uint16_t xs[BM * BK];   // 16 KB, swizzled A tile
    __shared__ __align__(16) uint16_t wt[BN * BK];   // 16 KB, swizzled W tile

    const int bx    = blockIdx.x;
    const int ks    = bx >> 9;          // 0..1  K-split half
    const int mtile = (bx >> 6) & 7;
    const int ntile = bx & 63;
    const int m0 = mtile * BM;
    const int n0 = ntile * BN;
    const int k0 = ks * (NK / 2);       // first kt of this block

    const int tid  = threadIdx.x;
    const int wave = tid >> 6;
    const int lane = tid & 63;
    const int wm = wave & 1, wn = wave >> 1;   // 64x64 wave subtile
    const int fr = lane & 15;
    const int quad = lane >> 4;

    const int qrow  = tid >> 4;
    const int qcol4 = (tid & 15) * 4;
    const int qhi   = (tid >> 3) & 1;
    const int wpos = ((((tid >> 1) & 7) ^ (qrow & 7)) * 8) + (tid & 1) * 4;

    const uint8_t* qbase = qu8 + (size_t)n0 * IN_F + qcol4;

    f32x4 acc[4][4];
    const f32x4 z = {0.f, 0.f, 0.f, 0.f};
#pragma unroll
    for (int i = 0; i < 4; ++i)
#pragma unroll
        for (int j = 0; j < 4; ++j) acc[i][j] = z;

    uint32_t qv[2][8];
    float    sc[2][8];

    // ---- prefetch q/scales for this block's first tile (kt = k0)
#pragma unroll
    for (int j = 0; j < 8; ++j) {
        const int row = qrow + 16 * j;
        qv[0][j] = *(const uint32_t*)(qbase + (size_t)row * IN_F + (size_t)k0 * BK);
        sc[0][j] = scales[(size_t)(n0 + row) * SCB + k0 * 2 + qhi];
    }

    // ---- LoRA prologue: ks==0 blocks only (block-uniform; contributes once)
    if (ks == 0) {
        if (tid < 128) {
            const int row = tid, s = row & 7;
            const float4* tp = (const float4*)(t + (size_t)(m0 + row) * RANK);
            const float4 v0 = tp[0], v1 = tp[1], v2 = tp[2], v3 = tp[3];
            uint32_t vals[8];
            vals[0] = pack_bf16(v0.x, v0.y); vals[1] = pack_bf16(v0.z, v0.w);
            vals[2] = pack_bf16(v1.x, v1.y); vals[3] = pack_bf16(v1.z, v1.w);
            vals[4] = pack_bf16(v2.x, v2.y); vals[5] = pack_bf16(v2.z, v2.w);
            vals[6] = pack_bf16(v3.x, v3.y); vals[7] = pack_bf16(v3.z, v3.w);
            uint32_t* dst = (uint32_t*)(&xs[row * BK]);
#pragma unroll
            for (int c = 0; c < 8; ++c) {
                const int p = (c ^ s) * 4;
                if (c < 2) {
                    dst[p + 0] = vals[c * 4 + 0]; dst[p + 1] = vals[c * 4 + 1];
                    dst[p + 2] = vals[c * 4 + 2]; dst[p + 3] = vals[c * 4 + 3];
                } else {
                    dst[p + 0] = 0; dst[p + 1] = 0; dst[p + 2] = 0; dst[p + 3] = 0;
                }
            }
        } else {
            const int row = tid - 128, s = row & 7;
            const float4* bp = (const float4*)(loraB + (size_t)(n0 + row) * RANK);
            const float4 v0 = bp[0], v1 = bp[1], v2 = bp[2], v3 = bp[3];
            uint32_t vals[8];
            vals[0] = pack_bf16(2.f * v0.x, 2.f * v0.y); vals[1] = pack_bf16(2.f * v0.z, 2.f * v0.w);
            vals[2] = pack_bf16(2.f * v1.x, 2.f * v1.y); vals[3] = pack_bf16(2.f * v1.z, 2.f * v1.w);
            vals[4] = pack_bf16(2.f * v2.x, 2.f * v2.y); vals[5] = pack_bf16(2.f * v2.z, 2.f * v2.w);
            vals[6] = pack_bf16(2.f * v3.x, 2.f * v3.y); vals[7] = pack_bf16(2.f * v3.z, 2.f * v3.w);
            uint32_t* dst = (uint32_t*)(&wt[row * BK]);
#pragma unroll
            for (int c = 0; c < 8; ++c) {
                const int p = (c ^ s) * 4;
                if (c < 2) {
                    dst[p + 0] = vals[c * 4 + 0]; dst[p + 1] = vals[c * 4 + 1];
                    dst[p + 2] = vals[c * 4 + 2]; dst[p + 3] = vals[c * 4 + 3];
                } else {
                    dst[p + 0] = 0; dst[p + 1] = 0; dst[p + 2] = 0; dst[p + 3] = 0;
                }
            }
        }
        __syncthreads();
        const int pp = (quad ^ (fr & 7)) * 8;    // chunk=quad; quads 2,3 read zeros
        bf16x8 af[4], bfr[4];
#pragma unroll
        for (int i = 0; i < 4; ++i)
            af[i] = *(const bf16x8*)(&xs[(wm * 64 + i * 16 + fr) * BK + pp]);
#pragma unroll
        for (int j = 0; j < 4; ++j)
            bfr[j] = *(const bf16x8*)(&wt[(wn * 64 + j * 16 + fr) * BK + pp]);
#pragma unroll
        for (int i = 0; i < 4; ++i)
#pragma unroll
            for (int j = 0; j < 4; ++j)
                acc[i][j] = __builtin_amdgcn_mfma_f32_16x16x32_bf16(af[i], bfr[j], acc[i][j], 0, 0, 0);
        __syncthreads();   // LoRA reads done before the first stage overwrites
    }

    // xs staging map: lane l stages row wave*32+(l>>3), global chunk
    // (l&7)^(l>>3), landing at LDS slot l&7 (swizzle via global perm).
    const int xrow   = wave * 32 + (lane >> 3);
    const int xchunk = (lane & 7) ^ (lane >> 3);
    const uint16_t* xsrc = xb + (size_t)(m0 + xrow) * IN_F + xchunk * 8;

    // ---- main loop: 64 kts, single-buffered, 2 barriers per kt
    for (int lt = 0; lt < NK / 2; lt += 2) {
        const int kt = k0 + lt;
        GEMM_STEP_S(kt,     k0 + ((lt + 1) & (NK / 2 - 1)), 0);
        GEMM_STEP_S(kt + 1, k0 + ((lt + 2) & (NK / 2 - 1)), 1);
    }

    // epilogue: store fp32 partial (no bias; C/D map: col=lane&15, row=quad*4+reg)
    float* pdst = part + (size_t)ks * M_TOT * OUT_F;
#pragma unroll
    for (int j = 0; j < 4; ++j) {
        const int col = n0 + wn * 64 + j * 16 + fr;
#pragma unroll
        for (int i = 0; i < 4; ++i) {
            const int rbase = m0 + wm * 64 + i * 16 + quad * 4;
#pragma unroll
            for (int r = 0; r < 4; ++r)
                pdst[(size_t)(rbase + r) * OUT_F + col] = acc[i][j][r];
        }
    }
}

// ---------------------------------------------------------------------------
// Kernel 4: out = p0 + p1 + bias. 96 MB traffic, coalesced float4.
// ---------------------------------------------------------------------------
__global__ __launch_bounds__(256) void reduce_kernel(
    const float4* __restrict__ p, const float* __restrict__ bias,
    float4* __restrict__ out4)
{
    const int idx = blockIdx.x * 256 + threadIdx.x;   // 2048 blocks -> 524288
    const float4* b4 = (const float4*)bias;
#pragma unroll
    for (int j = 0; j < 4; ++j) {
        const int f = idx + j * 524288;               // 2M float4 total
        const float4 a = p[f];
        const float4 b = p[f + 2097152];              // second 32 MB half
        const float4 bv = b4[f & 2047];               // bias row (L2-hot)
        float4 o;
        o.x = a.x + b.x + bv.x;
        o.y = a.y + b.y + bv.y;
        o.z = a.z + b.z + bv.z;
        o.w = a.w + b.w + bv.w;
        out4[f] = o;
    }
}

// ---------------------------------------------------------------------------
// Kernel 3B (u8 dbuf path, proven round-3 kernel): ws-short fallback.
// ---------------------------------------------------------------------------
#define GEMM_STEP_U(KT, P, CUR, NXT)                                           \
    {                                                                          \
        const int ktn = ((KT) + 2) & (NK - 1);                                 \
        _Pragma("unroll")                                                      \
        for (int j = 0; j < 8; ++j) {                                          \
            const int row = qrow + 16 * j;                                     \
            qv[(P) ^ 1][j] = *(const uint32_t*)(qbase + (size_t)row * IN_F + ktn * BK); \
            sc[(P) ^ 1][j] = scales[(size_t)(n0 + row) * SCB + ktn * 2 + qhi]; \
        }                                                                      \
        const int kta = ((KT) + 1) & (NK - 1);                                 \
        _Pragma("unroll")                                                      \
        for (int i = 0; i < 4; ++i) {                                          \
            __builtin_amdgcn_global_load_lds(                                  \
                (const __attribute__((address_space(1))) uint32_t*)(xsrc + (size_t)kta * BK + (size_t)i * 8 * IN_F), \
                (__attribute__((address_space(3))) uint32_t*)(&xs[NXT][(wave * 32 + i * 8) * BK]), \
                16, 0, 0);                                                     \
        }                                                                      \
        _Pragma("unroll")                                                      \
        for (int j = 0; j < 8; ++j) {                                          \
            const float s = sc[P][j];                                          \
            const float c = -128.f * s;                                        \
            const uint32_t qq = qv[P][j];                                      \
            uint2 pk;                                                          \
            pk.x = pack_bf16(fmaf((float)(qq & 0xffu), s, c),                  \
                             fmaf((float)((qq >> 8) & 0xffu), s, c));          \
            pk.y = pack_bf16(fmaf((float)((qq >> 16) & 0xffu), s, c),          \
                             fmaf((float)(qq >> 24), s, c));                   \
            *(uint2*)(&wt[NXT][(qrow + 16 * j) * BK + wpos]) = pk;             \
        }                                                                      \
        _Pragma("unroll")                                                      \
        for (int kk = 0; kk < BK; kk += 32) {                                  \
            bf16x8 af[4], bfr[4];                                              \
            const int pp = (((kk >> 3) + quad) ^ (fr & 7)) * 8;                \
            _Pragma("unroll")                                                  \
            for (int i = 0; i < 4; ++i)                                        \
                af[i] = *(const bf16x8*)(&xs[CUR][(wm * 64 + i * 16 + fr) * BK + pp]); \
            _Pragma("unroll")                                                  \
            for (int j = 0; j < 4; ++j)                                        \
                bfr[j] = *(const bf16x8*)(&wt[CUR][(wn * 64 + j * 16 + fr) * BK + pp]); \
            _Pragma("unroll")                                                  \
            for (int i = 0; i < 4; ++i)                                        \
                _Pragma("unroll")                                              \
                for (int j = 0; j < 4; ++j)                                    \
                    acc[i][j] = __builtin_amdgcn_mfma_f32_16x16x32_bf16(af[i], bfr[j], acc[i][j], 0, 0, 0); \
        }                                                                      \
        __syncthreads();                                                       \
    }

__global__ __launch_bounds__(256, 2) void gemm_u8_kernel(
    const uint16_t* __restrict__ xb,
    const uint8_t*  __restrict__ qu8,
    const float*    __restrict__ scales,
    const float*    __restrict__ t,
    const float*    __restrict__ loraB,
    const float*    __restrict__ bias,
    float*          __restrict__ out)
{
    __shared__ __align__(16) uint16_t xs[2][BM * BK];
    __shared__ __align__(16) uint16_t wt[2][BN * BK];

    const int bx    = blockIdx.x;
    const int mtile = bx >> 6;
    const int ntile = bx & 63;
    const int m0 = mtile * BM;
    const int n0 = ntile * BN;

    const int tid  = threadIdx.x;
    const int wave = tid >> 6;
    const int lane = tid & 63;
    const int wm = wave & 1, wn = wave >> 1;
    const int fr = lane & 15;
    const int quad = lane >> 4;

    const int qrow  = tid >> 4;
    const int qcol4 = (tid & 15) * 4;
    const int qhi   = (tid >> 3) & 1;
    const int wpos = ((((tid >> 1) & 7) ^ (qrow & 7)) * 8) + (tid & 1) * 4;

    const uint8_t* qbase = qu8 + (size_t)n0 * IN_F + qcol4;

    f32x4 acc[4][4];
    const f32x4 z = {0.f, 0.f, 0.f, 0.f};
#pragma unroll
    for (int i = 0; i < 4; ++i)
#pragma unroll
        for (int j = 0; j < 4; ++j) acc[i][j] = z;

    uint32_t qv[2][8];
    float    sc[2][8];

#pragma unroll
    for (int j = 0; j < 8; ++j) {
        const int row = qrow + 16 * j;
        qv[0][j] = *(const uint32_t*)(qbase + (size_t)row * IN_F);
        sc[0][j] = scales[(size_t)(n0 + row) * SCB + qhi];
    }

    {
        if (tid < 128) {
            const int row = tid, s = row & 7;
            const float4* tp = (const float4*)(t + (size_t)(m0 + row) * RANK);
            const float4 v0 = tp[0], v1 = tp[1], v2 = tp[2], v3 = tp[3];
            uint32_t vals[8];
            vals[0] = pack_bf16(v0.x, v0.y); vals[1] = pack_bf16(v0.z, v0.w);
            vals[2] = pack_bf16(v1.x, v1.y); vals[3] = pack_bf16(v1.z, v1.w);
            vals[4] = pack_bf16(v2.x, v2.y); vals[5] = pack_bf16(v2.z, v2.w);
            vals[6] = pack_bf16(v3.x, v3.y); vals[7] = pack_bf16(v3.z, v3.w);
            uint32_t* dst = (uint32_t*)(&xs[0][row * BK]);
#pragma unroll
            for (int c = 0; c < 8; ++c) {
                const int p = (c ^ s) * 4;
                if (c < 2) {
                    dst[p + 0] = vals[c * 4 + 0]; dst[p + 1] = vals[c * 4 + 1];
                    dst[p + 2] = vals[c * 4 + 2]; dst[p + 3] = vals[c * 4 + 3];
                } else {
                    dst[p + 0] = 0; dst[p + 1] = 0; dst[p + 2] = 0; dst[p + 3] = 0;
                }
            }
        } else {
            const int row = tid - 128, s = row & 7;
            const float4* bp = (const float4*)(loraB + (size_t)(n0 + row) * RANK);
            const float4 v0 = bp[0], v1 = bp[1], v2 = bp[2], v3 = bp[3];
            uint32_t vals[8];
            vals[0] = pack_bf16(2.f * v0.x, 2.f * v0.y); vals[1] = pack_bf16(2.f * v0.z, 2.f * v0.w);
            vals[2] = pack_bf16(2.f * v1.x, 2.f * v1.y); vals[3] = pack_bf16(2.f * v1.z, 2.f * v1.w);
            vals[4] = pack_bf16(2.f * v2.x, 2.f * v2.y); vals[5] = pack_bf16(2.f * v2.z, 2.f * v2.w);
            vals[6] = pack_bf16(2.f * v3.x, 2.f * v3.y); vals[7] = pack_bf16(2.f * v3.z, 2.f * v3.w);
            uint32_t* dst = (uint32_t*)(&wt[0][row * BK]);
#pragma unroll
            for (int c = 0; c < 8; ++c) {
                const int p = (c ^ s) * 4;
                if (c < 2) {
                    dst[p + 0] = vals[c * 4 + 0]; dst[p + 1] = vals[c * 4 + 1];
                    dst[p + 2] = vals[c * 4 + 2]; dst[p + 3] = vals[c * 4 + 3];
                } else {
                    dst[p + 0] = 0; dst[p + 1] = 0; dst[p + 2] = 0; dst[p + 3] = 0;
                }
            }
        }
        __syncthreads();
        const int pp = (quad ^ (fr & 7)) * 8;
        bf16x8 af[4], bfr[4];
#pragma unroll
        for (int i = 0; i < 4; ++i)
            af[i] = *(const bf16x8*)(&xs[0][(wm * 64 + i * 16 + fr) * BK + pp]);
#pragma unroll
        for (int j = 0; j < 4; ++j)
            bfr[j] = *(const bf16x8*)(&wt[0][(wn * 64 + j * 16 + fr) * BK + pp]);
#pragma unroll
        for (int i = 0; i < 4; ++i)
#pragma unroll
            for (int j = 0; j < 4; ++j)
                acc[i][j] = __builtin_amdgcn_mfma_f32_16x16x32_bf16(af[i], bfr[j], acc[i][j], 0, 0, 0);
        __syncthreads();
    }

    const int xrow   = wave * 32 + (lane >> 3);
    const int xchunk = (lane & 7) ^ (lane >> 3);
    const uint16_t* xsrc = xb + (size_t)(m0 + xrow) * IN_F + xchunk * 8;

#pragma unroll
    for (int i = 0; i < 4; ++i) {
        __builtin_amdgcn_global_load_lds(
            (const __attribute__((address_space(1))) uint32_t*)(xsrc + (size_t)i * 8 * IN_F),
            (__attribute__((address_space(3))) uint32_t*)(&xs[0][(wave * 32 + i * 8) * BK]),
            16, 0, 0);
    }
#pragma unroll
    for (int j = 0; j < 8; ++j) {
        const float s = sc[0][j];
        const float c = -128.f * s;
        const uint32_t qq = qv[0][j];
        uint2 pk;
        pk.x = pack_bf16(fmaf((float)(qq & 0xffu), s, c),
                         fmaf((float)((qq >> 8) & 0xffu), s, c));
        pk.y = pack_bf16(fmaf((float)((qq >> 16) & 0xffu), s, c),
                         fmaf((float)(qq >> 24), s, c));
        *(uint2*)(&wt[0][(qrow + 16 * j) * BK + wpos]) = pk;
    }
#pragma unroll
    for (int j = 0; j < 8; ++j) {
        const int row = qrow + 16 * j;
        qv[0][j] = *(const uint32_t*)(qbase + (size_t)row * IN_F + 1 * BK);
        sc[0][j] = scales[(size_t)(n0 + row) * SCB + 2 + qhi];
    }
    __syncthreads();

    for (int kt = 0; kt < NK; kt += 2) {
        GEMM_STEP_U(kt,     0, 0, 1);
        GEMM_STEP_U(kt + 1, 1, 1, 0);
    }

#pragma unroll
    for (int j = 0; j < 4; ++j) {
        const int col = n0 + wn * 64 + j * 16 + fr;
        const float bv = bias[col];
#pragma unroll
        for (int i = 0; i < 4; ++i) {
            const int rbase = m0 + wm * 64 + i * 16 + quad * 4;
#pragma unroll
            for (int r = 0; r < 4; ++r)
                out[(size_t)(rbase + r) * OUT_F + col] = acc[i][j][r] + bv;
        }
    }
}

extern "C" void kernel_launch(void* const* d_in, const int* in_sizes, int n_in,
                              void* d_out, int out_size, void* d_ws, size_t ws_size,
                              hipStream_t stream) {
    const float* x      = (const float*)d_in[0];
    const int*   q      = (const int*)d_in[1];
    const float* scales = (const float*)d_in[2];
    const float* lora_A = (const float*)d_in[3];
    const float* lora_B = (const float*)d_in[4];
    const float* bias   = (const float*)d_in[5];
    float* out = (float*)d_out;

    // ws layout: xb bf16 (16 MB) | t fp32 (64 KB) | qu8 (64 MB) | partials (64 MB)
    const size_t xb_bytes = (size_t)M_TOT * IN_F * sizeof(uint16_t);   // 16 MB
    const size_t t_bytes  = (size_t)M_TOT * RANK * sizeof(float);      // 64 KB
    const size_t q8_off   = xb_bytes + t_bytes;
    const size_t q8_bytes = (size_t)OUT_F * IN_F;                      // 64 MB
    const size_t p_off    = q8_off + q8_bytes;
    const size_t p_bytes  = (size_t)2 * M_TOT * OUT_F * sizeof(float); // 64 MB

    uint16_t* xb = (uint16_t*)d_ws;
    float*    t  = (float*)((char*)d_ws + xb_bytes);

    if (ws_size >= p_off + p_bytes) {
        uint8_t* qu8  = (uint8_t*)d_ws + q8_off;
        float*   part = (float*)((char*)d_ws + p_off);
        prep_kernel<<<2048, 256, 0, stream>>>(x, q, (uint2*)xb, (uint32_t*)qu8, t);
        lora_t_kernel<<<1024, 256, 0, stream>>>(xb, lora_A, t);
        gemm_u8s_kernel<<<2 * (M_TOT / BM) * (OUT_F / BN), 256, 0, stream>>>(
            xb, qu8, scales, t, lora_B, part);
        reduce_kernel<<<2048, 256, 0, stream>>>((const float4*)part, bias, (float4*)out);
    } else {
        // proven round-3 u8 path (needs 80.06 MB)
        uint8_t* qu8 = (uint8_t*)d_ws + q8_off;
        prep_kernel<<<2048, 256, 0, stream>>>(x, q, (uint2*)xb, (uint32_t*)qu8, t);
        lora_t_kernel<<<1024, 256, 0, stream>>>(xb, lora_A, t);
        gemm_u8_kernel<<<(M_TOT / BM) * (OUT_F / BN), 256, 0, stream>>>(
            xb, qu8, scales, t, lora_B, bias, out);
    }
}

// Round 7
// 887.947 us; speedup vs baseline: 1.5784x; 1.5784x over previous
//
#include <hip/hip_runtime.h>
#include <hip/hip_bf16.h>
#include <stdint.h>

#define OUT_F 8192
#define IN_F  8192
#define RANK  16
#define M_TOT 1024   // B*S
#define BM 128
#define BN 128
#define BK 64
#define NK (IN_F / BK)   // 128
#define SCB (IN_F / 32)  // 256 scale blocks per weight row

typedef __bf16 bf16x8 __attribute__((ext_vector_type(8)));
typedef float  f32x4  __attribute__((ext_vector_type(4)));

// round-half-up f32->bf16 pack of two floats into one uint32 (lo in low half)
static __device__ __forceinline__ uint32_t pack_bf16(float lo, float hi) {
    uint32_t a = __builtin_bit_cast(uint32_t, lo);
    uint32_t b = __builtin_bit_cast(uint32_t, hi);
    return ((a + 0x8000u) >> 16) | ((b + 0x8000u) & 0xffff0000u);
}

// ---------------------------------------------------------------------------
// Kernel 1 (prep, proven round-3): t zero + x fp32->bf16 + q int32->u8 narrow.
// ---------------------------------------------------------------------------
__global__ __launch_bounds__(256) void prep_kernel(
    const float* __restrict__ x, const int* __restrict__ q,
    uint2* __restrict__ xb2, uint32_t* __restrict__ qu32,
    float* __restrict__ t)
{
    const int gid = blockIdx.x * 256 + threadIdx.x;   // 0..524287 (2048 blocks)
    if (gid < M_TOT * RANK) t[gid] = 0.f;

    const float4* x4 = (const float4*)x;
#pragma unroll
    for (int j = 0; j < 4; ++j) {
        const int i = gid + j * 524288;
        const float4 v = x4[i];
        uint2 p;
        p.x = pack_bf16(v.x, v.y);
        p.y = pack_bf16(v.z, v.w);
        xb2[i] = p;
    }

    const int4* q4 = (const int4*)q;
#pragma unroll 8
    for (int k = 0; k < 32; ++k) {
        const size_t i = (size_t)gid + (size_t)k * 524288;
        const int4 a = q4[i];
        qu32[i] = (uint32_t)a.x | ((uint32_t)a.y << 8) |
                  ((uint32_t)a.z << 16) | ((uint32_t)a.w << 24);
    }
}

// ---------------------------------------------------------------------------
// Kernel 2: t = x @ lora_A^T via MFMA split-K + atomicAdd (reads xb bf16).
// ---------------------------------------------------------------------------
__global__ __launch_bounds__(256) void lora_t_kernel(
    const uint16_t* __restrict__ xb, const float* __restrict__ lora_A,
    float* __restrict__ t)
{
    const int b = blockIdx.x;           // 1024 blocks
    const int mt = b >> 6, ks = b & 63;
    const int tid = threadIdx.x, wave = tid >> 6, lane = tid & 63;
    const int fr = lane & 15, quad = lane >> 4;
    const int m = mt * 64 + wave * 16 + fr;
    const int k0 = ks * 128 + quad * 8;

    f32x4 acc = {0.f, 0.f, 0.f, 0.f};
    const uint16_t* xr = xb + (size_t)m * IN_F + k0;
    const float* ar = lora_A + (size_t)fr * IN_F + k0;

#pragma unroll
    for (int s = 0; s < 4; ++s) {
        const bf16x8 af = *(const bf16x8*)(xr + s * 32);
        const float4 a0 = *(const float4*)(ar + s * 32);
        const float4 a1 = *(const float4*)(ar + s * 32 + 4);
        bf16x8 bfr;
        uint32_t* bp = (uint32_t*)&bfr;
        bp[0] = pack_bf16(a0.x, a0.y); bp[1] = pack_bf16(a0.z, a0.w);
        bp[2] = pack_bf16(a1.x, a1.y); bp[3] = pack_bf16(a1.z, a1.w);
        acc = __builtin_amdgcn_mfma_f32_16x16x32_bf16(af, bfr, acc, 0, 0, 0);
    }
    const int mout = mt * 64 + wave * 16 + quad * 4;
#pragma unroll
    for (int r = 0; r < 4; ++r)
        atomicAdd(&t[(size_t)(mout + r) * RANK + fr], acc[r]);
}

// ---------------------------------------------------------------------------
// Kernel 3A (split-K u8, 3 blocks/CU): xs double-buffered (32 KB), wt single
// (16 KB) -> 48 KB LDS -> 3 blocks/CU. launch_bounds(256,3) -> <=170 regs/wave
// (needs ~150: acc 64 + qv/sc 16 single-set + frags 32 + addr). Step:
//   issue xs-DMA(kt+1)->xs[nxt]; MFMA(xs[cur], wt[kt]);    (MFMA covers DMA)
//   barrier;                                (all wt reads done; DMA drained)
//   dequant wt <- qv (kt+1 data); reload qv (kt+2);
//   barrier;                                (wt visible; qv in flight 1 step)
// Split-K=2 (grid 1024). LoRA contributes once (ks==0). Partials + reduce.
// ---------------------------------------------------------------------------
#define GEMM_STEP_S3(KTN1, KTN2, CUR, NXT)                                     \
    {                                                                          \
        _Pragma("unroll")                                                      \
        for (int i = 0; i < 4; ++i) {                                          \
            __builtin_amdgcn_global_load_lds(                                  \
                (const __attribute__((address_space(1))) uint32_t*)(xsrc + (size_t)(KTN1) * BK + (size_t)i * 8 * IN_F), \
                (__attribute__((address_space(3))) uint32_t*)(&xs[NXT][(wave * 32 + i * 8) * BK]), \
                16, 0, 0);                                                     \
        }                                                                      \
        _Pragma("unroll")                                                      \
        for (int kk = 0; kk < BK; kk += 32) {                                  \
            bf16x8 af[4], bfr[4];                                              \
            const int pp = (((kk >> 3) + quad) ^ (fr & 7)) * 8;                \
            _Pragma("unroll")                                                  \
            for (int i = 0; i < 4; ++i)                                        \
                af[i] = *(const bf16x8*)(&xs[CUR][(wm * 64 + i * 16 + fr) * BK + pp]); \
            _Pragma("unroll")                                                  \
            for (int j = 0; j < 4; ++j)                                        \
                bfr[j] = *(const bf16x8*)(&wt[(wn * 64 + j * 16 + fr) * BK + pp]); \
            _Pragma("unroll")                                                  \
            for (int i = 0; i < 4; ++i)                                        \
                _Pragma("unroll")                                              \
                for (int j = 0; j < 4; ++j)                                    \
                    acc[i][j] = __builtin_amdgcn_mfma_f32_16x16x32_bf16(af[i], bfr[j], acc[i][j], 0, 0, 0); \
        }                                                                      \
        __syncthreads();  /* wt reads + xs[NXT] DMA drained */                 \
        _Pragma("unroll")                                                      \
        for (int j = 0; j < 8; ++j) {                                          \
            const float s = sc[j];                                             \
            const float c = -128.f * s;                                        \
            const uint32_t qq = qv[j];                                         \
            uint2 pk;                                                          \
            pk.x = pack_bf16(fmaf((float)(qq & 0xffu), s, c),                  \
                             fmaf((float)((qq >> 8) & 0xffu), s, c));          \
            pk.y = pack_bf16(fmaf((float)((qq >> 16) & 0xffu), s, c),          \
                             fmaf((float)(qq >> 24), s, c));                   \
            *(uint2*)(&wt[(qrow + 16 * j) * BK + wpos]) = pk;                  \
        }                                                                      \
        _Pragma("unroll")                                                      \
        for (int j = 0; j < 8; ++j) {                                          \
            const int row = qrow + 16 * j;                                     \
            qv[j] = *(const uint32_t*)(qbase + (size_t)row * IN_F + (size_t)(KTN2) * BK); \
            sc[j] = scales[(size_t)(n0 + row) * SCB + (KTN2) * 2 + qhi];       \
        }                                                                      \
        __syncthreads();  /* wt(kt+1) visible */                               \
    }

__global__ __launch_bounds__(256, 3) void gemm_u8s3_kernel(
    const uint16_t* __restrict__ xb,    // bf16 x  [1024][8192] (in ws)
    const uint8_t*  __restrict__ qu8,   // u8      [8192][8192] (in ws)
    const float*    __restrict__ scales,// fp32    [8192][256]
    const float*    __restrict__ t,     // fp32    [1024][16]   (in ws)
    const float*    __restrict__ loraB, // fp32    [8192][16]
    float*          __restrict__ part)  // fp32    [2][1024][8192] partials (ws)
{
    __shared__ __align__(16) uint16_t xs[2][BM * BK];   // 32 KB, swizzled A dbuf
    __shared__ __align__(16) uint16_t wt[BN * BK];      // 16 KB, swizzled W single

    const int bx    = blockIdx.x;
    const int ks    = bx >> 9;          // 0..1  K-split half
    const int mtile = (bx >> 6) & 7;
    const int ntile = bx & 63;
    const int m0 = mtile * BM;
    const int n0 = ntile * BN;
    const int k0 = ks * (NK / 2);       // first kt of this block

    const int tid  = threadIdx.x;
    const int wave = tid >> 6;
    const int lane = tid & 63;
    const int wm = wave & 1, wn = wave >> 1;   // 64x64 wave subtile
    const int fr = lane & 15;
    const int quad = lane >> 4;

    const int qrow  = tid >> 4;
    const int qcol4 = (tid & 15) * 4;
    const int qhi   = (tid >> 3) & 1;
    const int wpos = ((((tid >> 1) & 7) ^ (qrow & 7)) * 8) + (tid & 1) * 4;

    const uint8_t* qbase = qu8 + (size_t)n0 * IN_F + qcol4;

    f32x4 acc[4][4];
    const f32x4 z = {0.f, 0.f, 0.f, 0.f};
#pragma unroll
    for (int i = 0; i < 4; ++i)
#pragma unroll
        for (int j = 0; j < 4; ++j) acc[i][j] = z;

    uint32_t qv[8];
    float    sc[8];

    // ---- prefetch q/scales for kt = k0
#pragma unroll
    for (int j = 0; j < 8; ++j) {
        const int row = qrow + 16 * j;
        qv[j] = *(const uint32_t*)(qbase + (size_t)row * IN_F + (size_t)k0 * BK);
        sc[j] = scales[(size_t)(n0 + row) * SCB + k0 * 2 + qhi];
    }

    // ---- LoRA prologue: ks==0 blocks only (block-uniform; contributes once)
    if (ks == 0) {
        if (tid < 128) {
            const int row = tid, s = row & 7;
            const float4* tp = (const float4*)(t + (size_t)(m0 + row) * RANK);
            const float4 v0 = tp[0], v1 = tp[1], v2 = tp[2], v3 = tp[3];
            uint32_t vals[8];
            vals[0] = pack_bf16(v0.x, v0.y); vals[1] = pack_bf16(v0.z, v0.w);
            vals[2] = pack_bf16(v1.x, v1.y); vals[3] = pack_bf16(v1.z, v1.w);
            vals[4] = pack_bf16(v2.x, v2.y); vals[5] = pack_bf16(v2.z, v2.w);
            vals[6] = pack_bf16(v3.x, v3.y); vals[7] = pack_bf16(v3.z, v3.w);
            uint32_t* dst = (uint32_t*)(&xs[0][row * BK]);
#pragma unroll
            for (int c = 0; c < 8; ++c) {
                const int p = (c ^ s) * 4;
                if (c < 2) {
                    dst[p + 0] = vals[c * 4 + 0]; dst[p + 1] = vals[c * 4 + 1];
                    dst[p + 2] = vals[c * 4 + 2]; dst[p + 3] = vals[c * 4 + 3];
                } else {
                    dst[p + 0] = 0; dst[p + 1] = 0; dst[p + 2] = 0; dst[p + 3] = 0;
                }
            }
        } else {
            const int row = tid - 128, s = row & 7;
            const float4* bp = (const float4*)(loraB + (size_t)(n0 + row) * RANK);
            const float4 v0 = bp[0], v1 = bp[1], v2 = bp[2], v3 = bp[3];
            uint32_t vals[8];
            vals[0] = pack_bf16(2.f * v0.x, 2.f * v0.y); vals[1] = pack_bf16(2.f * v0.z, 2.f * v0.w);
            vals[2] = pack_bf16(2.f * v1.x, 2.f * v1.y); vals[3] = pack_bf16(2.f * v1.z, 2.f * v1.w);
            vals[4] = pack_bf16(2.f * v2.x, 2.f * v2.y); vals[5] = pack_bf16(2.f * v2.z, 2.f * v2.w);
            vals[6] = pack_bf16(2.f * v3.x, 2.f * v3.y); vals[7] = pack_bf16(2.f * v3.z, 2.f * v3.w);
            uint32_t* dst = (uint32_t*)(&wt[row * BK]);
#pragma unroll
            for (int c = 0; c < 8; ++c) {
                const int p = (c ^ s) * 4;
                if (c < 2) {
                    dst[p + 0] = vals[c * 4 + 0]; dst[p + 1] = vals[c * 4 + 1];
                    dst[p + 2] = vals[c * 4 + 2]; dst[p + 3] = vals[c * 4 + 3];
                } else {
                    dst[p + 0] = 0; dst[p + 1] = 0; dst[p + 2] = 0; dst[p + 3] = 0;
                }
            }
        }
        __syncthreads();
        const int pp = (quad ^ (fr & 7)) * 8;    // chunk=quad; quads 2,3 read zeros
        bf16x8 af[4], bfr[4];
#pragma unroll
        for (int i = 0; i < 4; ++i)
            af[i] = *(const bf16x8*)(&xs[0][(wm * 64 + i * 16 + fr) * BK + pp]);
#pragma unroll
        for (int j = 0; j < 4; ++j)
            bfr[j] = *(const bf16x8*)(&wt[(wn * 64 + j * 16 + fr) * BK + pp]);
#pragma unroll
        for (int i = 0; i < 4; ++i)
#pragma unroll
            for (int j = 0; j < 4; ++j)
                acc[i][j] = __builtin_amdgcn_mfma_f32_16x16x32_bf16(af[i], bfr[j], acc[i][j], 0, 0, 0);
        __syncthreads();   // LoRA reads done before wt/xs are restaged
    }

    // xs staging map: lane l stages row wave*32+(l>>3), global chunk
    // (l&7)^(l>>3), landing at LDS slot l&7 (swizzle via global perm).
    const int xrow   = wave * 32 + (lane >> 3);
    const int xchunk = (lane & 7) ^ (lane >> 3);
    const uint16_t* xsrc = xb + (size_t)(m0 + xrow) * IN_F + xchunk * 8;

    // ---- pipeline prologue: stage xs[0](k0) DMA, write wt(k0) from qv,
    // reload qv(k0+1), barrier -> loop entry state {cur=0, wt=k0, qv=k0+1}.
#pragma unroll
    for (int i = 0; i < 4; ++i) {
        __builtin_amdgcn_global_load_lds(
            (const __attribute__((address_space(1))) uint32_t*)(xsrc + (size_t)k0 * BK + (size_t)i * 8 * IN_F),
            (__attribute__((address_space(3))) uint32_t*)(&xs[0][(wave * 32 + i * 8) * BK]),
            16, 0, 0);
    }
#pragma unroll
    for (int j = 0; j < 8; ++j) {
        const float s = sc[j];
        const float c = -128.f * s;
        const uint32_t qq = qv[j];
        uint2 pk;
        pk.x = pack_bf16(fmaf((float)(qq & 0xffu), s, c),
                         fmaf((float)((qq >> 8) & 0xffu), s, c));
        pk.y = pack_bf16(fmaf((float)((qq >> 16) & 0xffu), s, c),
                         fmaf((float)(qq >> 24), s, c));
        *(uint2*)(&wt[(qrow + 16 * j) * BK + wpos]) = pk;
    }
#pragma unroll
    for (int j = 0; j < 8; ++j) {
        const int row = qrow + 16 * j;
        qv[j] = *(const uint32_t*)(qbase + (size_t)row * IN_F + (size_t)(k0 + 1) * BK);
        sc[j] = scales[(size_t)(n0 + row) * SCB + (k0 + 1) * 2 + qhi];
    }
    __syncthreads();

    // ---- main loop: 64 kts, 2 barriers/kt, ping-pong xs only
    for (int lt = 0; lt < NK / 2; lt += 2) {
        GEMM_STEP_S3(k0 + ((lt + 1) & (NK / 2 - 1)), k0 + ((lt + 2) & (NK / 2 - 1)), 0, 1);
        GEMM_STEP_S3(k0 + ((lt + 2) & (NK / 2 - 1)), k0 + ((lt + 3) & (NK / 2 - 1)), 1, 0);
    }

    // epilogue: store fp32 partial (no bias; C/D map: col=lane&15, row=quad*4+reg)
    float* pdst = part + (size_t)ks * M_TOT * OUT_F;
#pragma unroll
    for (int j = 0; j < 4; ++j) {
        const int col = n0 + wn * 64 + j * 16 + fr;
#pragma unroll
        for (int i = 0; i < 4; ++i) {
            const int rbase = m0 + wm * 64 + i * 16 + quad * 4;
#pragma unroll
            for (int r = 0; r < 4; ++r)
                pdst[(size_t)(rbase + r) * OUT_F + col] = acc[i][j][r];
        }
    }
}

// ---------------------------------------------------------------------------
// Kernel 4: out = p0 + p1 + bias (proven round-5). 96 MB traffic, float4.
// ---------------------------------------------------------------------------
__global__ __launch_bounds__(256) void reduce_kernel(
    const float4* __restrict__ p, const float* __restrict__ bias,
    float4* __restrict__ out4)
{
    const int idx = blockIdx.x * 256 + threadIdx.x;   // 2048 blocks -> 524288
    const float4* b4 = (const float4*)bias;
#pragma unroll
    for (int j = 0; j < 4; ++j) {
        const int f = idx + j * 524288;               // 2M float4 total
        const float4 a = p[f];
        const float4 b = p[f + 2097152];              // second 32 MB half
        const float4 bv = b4[f & 2047];               // bias row (L2-hot)
        float4 o;
        o.x = a.x + b.x + bv.x;
        o.y = a.y + b.y + bv.y;
        o.z = a.z + b.z + bv.z;
        o.w = a.w + b.w + bv.w;
        out4[f] = o;
    }
}

// ---------------------------------------------------------------------------
// Kernel 3B (u8 dbuf path, proven round-3 kernel): ws-short fallback.
// ---------------------------------------------------------------------------
#define GEMM_STEP_U(KT, P, CUR, NXT)                                           \
    {                                                                          \
        const int ktn = ((KT) + 2) & (NK - 1);                                 \
        _Pragma("unroll")                                                      \
        for (int j = 0; j < 8; ++j) {                                          \
            const int row = qrow + 16 * j;                                     \
            qv[(P) ^ 1][j] = *(const uint32_t*)(qbase + (size_t)row * IN_F + ktn * BK); \
            sc[(P) ^ 1][j] = scales[(size_t)(n0 + row) * SCB + ktn * 2 + qhi]; \
        }                                                                      \
        const int kta = ((KT) + 1) & (NK - 1);                                 \
        _Pragma("unroll")                                                      \
        for (int i = 0; i < 4; ++i) {                                          \
            __builtin_amdgcn_global_load_lds(                                  \
                (const __attribute__((address_space(1))) uint32_t*)(xsrc + (size_t)kta * BK + (size_t)i * 8 * IN_F), \
                (__attribute__((address_space(3))) uint32_t*)(&xs[NXT][(wave * 32 + i * 8) * BK]), \
                16, 0, 0);                                                     \
        }                                                                      \
        _Pragma("unroll")                                                      \
        for (int j = 0; j < 8; ++j) {                                          \
            const float s = sc[P][j];                                          \
            const float c = -128.f * s;                                        \
            const uint32_t qq = qv[P][j];                                      \
            uint2 pk;                                                          \
            pk.x = pack_bf16(fmaf((float)(qq & 0xffu), s, c),                  \
                             fmaf((float)((qq >> 8) & 0xffu), s, c));          \
            pk.y = pack_bf16(fmaf((float)((qq >> 16) & 0xffu), s, c),          \
                             fmaf((float)(qq >> 24), s, c));                   \
            *(uint2*)(&wt[NXT][(qrow + 16 * j) * BK + wpos]) = pk;             \
        }                                                                      \
        _Pragma("unroll")                                                      \
        for (int kk = 0; kk < BK; kk += 32) {                                  \
            bf16x8 af[4], bfr[4];                                              \
            const int pp = (((kk >> 3) + quad) ^ (fr & 7)) * 8;                \
            _Pragma("unroll")                                                  \
            for (int i = 0; i < 4; ++i)                                        \
                af[i] = *(const bf16x8*)(&xs[CUR][(wm * 64 + i * 16 + fr) * BK + pp]); \
            _Pragma("unroll")                                                  \
            for (int j = 0; j < 4; ++j)                                        \
                bfr[j] = *(const bf16x8*)(&wt[CUR][(wn * 64 + j * 16 + fr) * BK + pp]); \
            _Pragma("unroll")                                                  \
            for (int i = 0; i < 4; ++i)                                        \
                _Pragma("unroll")                                              \
                for (int j = 0; j < 4; ++j)                                    \
                    acc[i][j] = __builtin_amdgcn_mfma_f32_16x16x32_bf16(af[i], bfr[j], acc[i][j], 0, 0, 0); \
        }                                                                      \
        __syncthreads();                                                       \
    }

__global__ __launch_bounds__(256, 2) void gemm_u8_kernel(
    const uint16_t* __restrict__ xb,
    const uint8_t*  __restrict__ qu8,
    const float*    __restrict__ scales,
    const float*    __restrict__ t,
    const float*    __restrict__ loraB,
    const float*    __restrict__ bias,
    float*          __restrict__ out)
{
    __shared__ __align__(16) uint16_t xs[2][BM * BK];
    __shared__ __align__(16) uint16_t wt[2][BN * BK];

    const int bx    = blockIdx.x;
    const int mtile = bx >> 6;
    const int ntile = bx & 63;
    const int m0 = mtile * BM;
    const int n0 = ntile * BN;

    const int tid  = threadIdx.x;
    const int wave = tid >> 6;
    const int lane = tid & 63;
    const int wm = wave & 1, wn = wave >> 1;
    const int fr = lane & 15;
    const int quad = lane >> 4;

    const int qrow  = tid >> 4;
    const int qcol4 = (tid & 15) * 4;
    const int qhi   = (tid >> 3) & 1;
    const int wpos = ((((tid >> 1) & 7) ^ (qrow & 7)) * 8) + (tid & 1) * 4;

    const uint8_t* qbase = qu8 + (size_t)n0 * IN_F + qcol4;

    f32x4 acc[4][4];
    const f32x4 z = {0.f, 0.f, 0.f, 0.f};
#pragma unroll
    for (int i = 0; i < 4; ++i)
#pragma unroll
        for (int j = 0; j < 4; ++j) acc[i][j] = z;

    uint32_t qv[2][8];
    float    sc[2][8];

#pragma unroll
    for (int j = 0; j < 8; ++j) {
        const int row = qrow + 16 * j;
        qv[0][j] = *(const uint32_t*)(qbase + (size_t)row * IN_F);
        sc[0][j] = scales[(size_t)(n0 + row) * SCB + qhi];
    }

    {
        if (tid < 128) {
            const int row = tid, s = row & 7;
            const float4* tp = (const float4*)(t + (size_t)(m0 + row) * RANK);
            const float4 v0 = tp[0], v1 = tp[1], v2 = tp[2], v3 = tp[3];
            uint32_t vals[8];
            vals[0] = pack_bf16(v0.x, v0.y); vals[1] = pack_bf16(v0.z, v0.w);
            vals[2] = pack_bf16(v1.x, v1.y); vals[3] = pack_bf16(v1.z, v1.w);
            vals[4] = pack_bf16(v2.x, v2.y); vals[5] = pack_bf16(v2.z, v2.w);
            vals[6] = pack_bf16(v3.x, v3.y); vals[7] = pack_bf16(v3.z, v3.w);
            uint32_t* dst = (uint32_t*)(&xs[0][row * BK]);
#pragma unroll
            for (int c = 0; c < 8; ++c) {
                const int p = (c ^ s) * 4;
                if (c < 2) {
                    dst[p + 0] = vals[c * 4 + 0]; dst[p + 1] = vals[c * 4 + 1];
                    dst[p + 2] = vals[c * 4 + 2]; dst[p + 3] = vals[c * 4 + 3];
                } else {
                    dst[p + 0] = 0; dst[p + 1] = 0; dst[p + 2] = 0; dst[p + 3] = 0;
                }
            }
        } else {
            const int row = tid - 128, s = row & 7;
            const float4* bp = (const float4*)(loraB + (size_t)(n0 + row) * RANK);
            const float4 v0 = bp[0], v1 = bp[1], v2 = bp[2], v3 = bp[3];
            uint32_t vals[8];
            vals[0] = pack_bf16(2.f * v0.x, 2.f * v0.y); vals[1] = pack_bf16(2.f * v0.z, 2.f * v0.w);
            vals[2] = pack_bf16(2.f * v1.x, 2.f * v1.y); vals[3] = pack_bf16(2.f * v1.z, 2.f * v1.w);
            vals[4] = pack_bf16(2.f * v2.x, 2.f * v2.y); vals[5] = pack_bf16(2.f * v2.z, 2.f * v2.w);
            vals[6] = pack_bf16(2.f * v3.x, 2.f * v3.y); vals[7] = pack_bf16(2.f * v3.z, 2.f * v3.w);
            uint32_t* dst = (uint32_t*)(&wt[0][row * BK]);
#pragma unroll
            for (int c = 0; c < 8; ++c) {
                const int p = (c ^ s) * 4;
                if (c < 2) {
                    dst[p + 0] = vals[c * 4 + 0]; dst[p + 1] = vals[c * 4 + 1];
                    dst[p + 2] = vals[c * 4 + 2]; dst[p + 3] = vals[c * 4 + 3];
                } else {
                    dst[p + 0] = 0; dst[p + 1] = 0; dst[p + 2] = 0; dst[p + 3] = 0;
                }
            }
        }
        __syncthreads();
        const int pp = (quad ^ (fr & 7)) * 8;
        bf16x8 af[4], bfr[4];
#pragma unroll
        for (int i = 0; i < 4; ++i)
            af[i] = *(const bf16x8*)(&xs[0][(wm * 64 + i * 16 + fr) * BK + pp]);
#pragma unroll
        for (int j = 0; j < 4; ++j)
            bfr[j] = *(const bf16x8*)(&wt[0][(wn * 64 + j * 16 + fr) * BK + pp]);
#pragma unroll
        for (int i = 0; i < 4; ++i)
#pragma unroll
            for (int j = 0; j < 4; ++j)
                acc[i][j] = __builtin_amdgcn_mfma_f32_16x16x32_bf16(af[i], bfr[j], acc[i][j], 0, 0, 0);
        __syncthreads();
    }

    const int xrow   = wave * 32 + (lane >> 3);
    const int xchunk = (lane & 7) ^ (lane >> 3);
    const uint16_t* xsrc = xb + (size_t)(m0 + xrow) * IN_F + xchunk * 8;

#pragma unroll
    for (int i = 0; i < 4; ++i) {
        __builtin_amdgcn_global_load_lds(
            (const __attribute__((address_space(1))) uint32_t*)(xsrc + (size_t)i * 8 * IN_F),
            (__attribute__((address_space(3))) uint32_t*)(&xs[0][(wave * 32 + i * 8) * BK]),
            16, 0, 0);
    }
#pragma unroll
    for (int j = 0; j < 8; ++j) {
        const float s = sc[0][j];
        const float c = -128.f * s;
        const uint32_t qq = qv[0][j];
        uint2 pk;
        pk.x = pack_bf16(fmaf((float)(qq & 0xffu), s, c),
                         fmaf((float)((qq >> 8) & 0xffu), s, c));
        pk.y = pack_bf16(fmaf((float)((qq >> 16) & 0xffu), s, c),
                         fmaf((float)(qq >> 24), s, c));
        *(uint2*)(&wt[0][(qrow + 16 * j) * BK + wpos]) = pk;
    }
#pragma unroll
    for (int j = 0; j < 8; ++j) {
        const int row = qrow + 16 * j;
        qv[0][j] = *(const uint32_t*)(qbase + (size_t)row * IN_F + 1 * BK);
        sc[0][j] = scales[(size_t)(n0 + row) * SCB + 2 + qhi];
    }
    __syncthreads();

    for (int kt = 0; kt < NK; kt += 2) {
        GEMM_STEP_U(kt,     0, 0, 1);
        GEMM_STEP_U(kt + 1, 1, 1, 0);
    }

#pragma unroll
    for (int j = 0; j < 4; ++j) {
        const int col = n0 + wn * 64 + j * 16 + fr;
        const float bv = bias[col];
#pragma unroll
        for (int i = 0; i < 4; ++i) {
            const int rbase = m0 + wm * 64 + i * 16 + quad * 4;
#pragma unroll
            for (int r = 0; r < 4; ++r)
                out[(size_t)(rbase + r) * OUT_F + col] = acc[i][j][r] + bv;
        }
    }
}

extern "C" void kernel_launch(void* const* d_in, const int* in_sizes, int n_in,
                              void* d_out, int out_size, void* d_ws, size_t ws_size,
                              hipStream_t stream) {
    const float* x      = (const float*)d_in[0];
    const int*   q      = (const int*)d_in[1];
    const float* scales = (const float*)d_in[2];
    const float* lora_A = (const float*)d_in[3];
    const float* lora_B = (const float*)d_in[4];
    const float* bias   = (const float*)d_in[5];
    float* out = (float*)d_out;

    // ws layout: xb bf16 (16 MB) | t fp32 (64 KB) | qu8 (64 MB) | partials (64 MB)
    const size_t xb_bytes = (size_t)M_TOT * IN_F * sizeof(uint16_t);   // 16 MB
    const size_t t_bytes  = (size_t)M_TOT * RANK * sizeof(float);      // 64 KB
    const size_t q8_off   = xb_bytes + t_bytes;
    const size_t q8_bytes = (size_t)OUT_F * IN_F;                      // 64 MB
    const size_t p_off    = q8_off + q8_bytes;
    const size_t p_bytes  = (size_t)2 * M_TOT * OUT_F * sizeof(float); // 64 MB

    uint16_t* xb = (uint16_t*)d_ws;
    float*    t  = (float*)((char*)d_ws + xb_bytes);

    if (ws_size >= p_off + p_bytes) {
        uint8_t* qu8  = (uint8_t*)d_ws + q8_off;
        float*   part = (float*)((char*)d_ws + p_off);
        prep_kernel<<<2048, 256, 0, stream>>>(x, q, (uint2*)xb, (uint32_t*)qu8, t);
        lora_t_kernel<<<1024, 256, 0, stream>>>(xb, lora_A, t);
        gemm_u8s3_kernel<<<2 * (M_TOT / BM) * (OUT_F / BN), 256, 0, stream>>>(
            xb, qu8, scales, t, lora_B, part);
        reduce_kernel<<<2048, 256, 0, stream>>>((const float4*)part, bias, (float4*)out);
    } else {
        // proven round-3 u8 path (needs 80.06 MB)
        uint8_t* qu8 = (uint8_t*)d_ws + q8_off;
        prep_kernel<<<2048, 256, 0, stream>>>(x, q, (uint2*)xb, (uint32_t*)qu8, t);
        lora_t_kernel<<<1024, 256, 0, stream>>>(xb, lora_A, t);
        gemm_u8_kernel<<<(M_TOT / BM) * (OUT_F / BN), 256, 0, stream>>>(
            xb, qu8, scales, t, lora_B, bias, out);
    }
}

// Round 8
// 601.812 us; speedup vs baseline: 2.3289x; 1.4755x over previous
//
#include <hip/hip_runtime.h>
#include <hip/hip_bf16.h>
#include <stdint.h>

#define OUT_F 8192
#define IN_F  8192
#define RANK  16
#define M_TOT 1024   // B*S
#define BM 128
#define BN 128
#define BK 64
#define NK (IN_F / BK)   // 128
#define SCB (IN_F / 32)  // 256 scale blocks per weight row

typedef __bf16 bf16x8 __attribute__((ext_vector_type(8)));
typedef float  f32x4  __attribute__((ext_vector_type(4)));

// round-half-up f32->bf16 pack of two floats into one uint32 (lo in low half)
static __device__ __forceinline__ uint32_t pack_bf16(float lo, float hi) {
    uint32_t a = __builtin_bit_cast(uint32_t, lo);
    uint32_t b = __builtin_bit_cast(uint32_t, hi);
    return ((a + 0x8000u) >> 16) | ((b + 0x8000u) & 0xffff0000u);
}

// ---------------------------------------------------------------------------
// Kernel 1 (fused prep): one streaming pass doing
//   - t zero (first 16384 threads)
//   - x fp32 -> bf16 into xb (48 MB traffic)
//   - q int32 -> u8 narrow into qu8, IDENTICAL [o][i] layout (320 MB traffic)
// All loads lane-contiguous (16 B/lane int4 reads -> 1 KB/wave/instr).
// ---------------------------------------------------------------------------
__global__ __launch_bounds__(256) void prep_kernel(
    const float* __restrict__ x, const int* __restrict__ q,
    uint2* __restrict__ xb2, uint32_t* __restrict__ qu32,
    float* __restrict__ t)
{
    const int gid = blockIdx.x * 256 + threadIdx.x;   // 0..524287 (2048 blocks)
    if (gid < M_TOT * RANK) t[gid] = 0.f;

    // x: 2M float4, 4 per thread, grid-strided (coalesced)
    const float4* x4 = (const float4*)x;
#pragma unroll
    for (int j = 0; j < 4; ++j) {
        const int i = gid + j * 524288;
        const float4 v = x4[i];
        uint2 p;
        p.x = pack_bf16(v.x, v.y);
        p.y = pack_bf16(v.z, v.w);
        xb2[i] = p;
    }

    // q: 16M int4 chunks (64M ints), 32 per thread, grid-strided (coalesced)
    const int4* q4 = (const int4*)q;
#pragma unroll 8
    for (int k = 0; k < 32; ++k) {
        const size_t i = (size_t)gid + (size_t)k * 524288;
        const int4 a = q4[i];
        qu32[i] = (uint32_t)a.x | ((uint32_t)a.y << 8) |
                  ((uint32_t)a.z << 16) | ((uint32_t)a.w << 24);
    }
}

// ---------------------------------------------------------------------------
// Kernel 1f (fallback prep when ws can't hold qu8): x convert + t zero only.
// ---------------------------------------------------------------------------
__global__ __launch_bounds__(256) void convert_kernel(
    const float* __restrict__ x, uint2* __restrict__ xb2, float* __restrict__ t)
{
    const int tid = threadIdx.x, b = blockIdx.x;
    if (b < 64) t[b * 256 + tid] = 0.f;
    const float4* x4 = (const float4*)x;
    const int base = b * 256 + tid;
#pragma unroll
    for (int j = 0; j < 8; ++j) {
        const int i = base + j * 262144;       // 2M float4 total
        const float4 v = x4[i];
        uint2 p;
        p.x = pack_bf16(v.x, v.y);
        p.y = pack_bf16(v.z, v.w);
        xb2[i] = p;
    }
}

// ---------------------------------------------------------------------------
// Kernel 2: t = x @ lora_A^T via MFMA split-K + atomicAdd.
// Split-k 64 (1024 blocks -> 4 blocks/CU, 16 waves/CU), reads xb (bf16 packed
// by prep, bit-identical values) -> no x-side pack VALU, half the x bytes.
// ---------------------------------------------------------------------------
__global__ __launch_bounds__(256) void lora_t_kernel(
    const uint16_t* __restrict__ xb, const float* __restrict__ lora_A,
    float* __restrict__ t)
{
    const int b = blockIdx.x;           // 1024 blocks
    const int mt = b >> 6, ks = b & 63;
    const int tid = threadIdx.x, wave = tid >> 6, lane = tid & 63;
    const int fr = lane & 15, quad = lane >> 4;
    const int m = mt * 64 + wave * 16 + fr;
    const int k0 = ks * 128 + quad * 8;

    f32x4 acc = {0.f, 0.f, 0.f, 0.f};
    const uint16_t* xr = xb + (size_t)m * IN_F + k0;
    const float* ar = lora_A + (size_t)fr * IN_F + k0;

#pragma unroll
    for (int s = 0; s < 4; ++s) {
        const bf16x8 af = *(const bf16x8*)(xr + s * 32);
        const float4 a0 = *(const float4*)(ar + s * 32);
        const float4 a1 = *(const float4*)(ar + s * 32 + 4);
        bf16x8 bfr;
        uint32_t* bp = (uint32_t*)&bfr;
        bp[0] = pack_bf16(a0.x, a0.y); bp[1] = pack_bf16(a0.z, a0.w);
        bp[2] = pack_bf16(a1.x, a1.y); bp[3] = pack_bf16(a1.z, a1.w);
        acc = __builtin_amdgcn_mfma_f32_16x16x32_bf16(af, bfr, acc, 0, 0, 0);
    }
    const int mout = mt * 64 + wave * 16 + quad * 4;
#pragma unroll
    for (int r = 0; r < 4; ++r)
        atomicAdd(&t[(size_t)(mout + r) * RANK + fr], acc[r]);
}

// ---------------------------------------------------------------------------
// Kernel 3 (u8 path, proven 217us): double-buffered 64 KB LDS, 2 blocks/CU,
// one barrier per kt; every vmem op issued a full kt before the barrier that
// drains it. q loads are uint32 (4 u8 cols); dequant unpacks bytes.
// ---------------------------------------------------------------------------
#define GEMM_STEP_U(KT, P, CUR, NXT)                                           \
    {                                                                          \
        const int ktn = ((KT) + 2) & (NK - 1);                                 \
        _Pragma("unroll")                                                      \
        for (int j = 0; j < 8; ++j) {                                          \
            const int row = qrow + 16 * j;                                     \
            qv[(P) ^ 1][j] = *(const uint32_t*)(qbase + (size_t)row * IN_F + ktn * BK); \
            sc[(P) ^ 1][j] = scales[(size_t)(n0 + row) * SCB + ktn * 2 + qhi]; \
        }                                                                      \
        const int kta = ((KT) + 1) & (NK - 1);                                 \
        _Pragma("unroll")                                                      \
        for (int i = 0; i < 4; ++i) {                                          \
            __builtin_amdgcn_global_load_lds(                                  \
                (const __attribute__((address_space(1))) uint32_t*)(xsrc + (size_t)kta * BK + (size_t)i * 8 * IN_F), \
                (__attribute__((address_space(3))) uint32_t*)(&xs[NXT][(wave * 32 + i * 8) * BK]), \
                16, 0, 0);                                                     \
        }                                                                      \
        _Pragma("unroll")                                                      \
        for (int j = 0; j < 8; ++j) {                                          \
            const float s = sc[P][j];                                          \
            const float c = -128.f * s;                                        \
            const uint32_t qq = qv[P][j];                                      \
            uint2 pk;                                                          \
            pk.x = pack_bf16(fmaf((float)(qq & 0xffu), s, c),                  \
                             fmaf((float)((qq >> 8) & 0xffu), s, c));          \
            pk.y = pack_bf16(fmaf((float)((qq >> 16) & 0xffu), s, c),          \
                             fmaf((float)(qq >> 24), s, c));                   \
            *(uint2*)(&wt[NXT][(qrow + 16 * j) * BK + wpos]) = pk;             \
        }                                                                      \
        _Pragma("unroll")                                                      \
        for (int kk = 0; kk < BK; kk += 32) {                                  \
            bf16x8 af[4], bfr[4];                                              \
            const int pp = (((kk >> 3) + quad) ^ (fr & 7)) * 8;                \
            _Pragma("unroll")                                                  \
            for (int i = 0; i < 4; ++i)                                        \
                af[i] = *(const bf16x8*)(&xs[CUR][(wm * 64 + i * 16 + fr) * BK + pp]); \
            _Pragma("unroll")                                                  \
            for (int j = 0; j < 4; ++j)                                        \
                bfr[j] = *(const bf16x8*)(&wt[CUR][(wn * 64 + j * 16 + fr) * BK + pp]); \
            _Pragma("unroll")                                                  \
            for (int i = 0; i < 4; ++i)                                        \
                _Pragma("unroll")                                              \
                for (int j = 0; j < 4; ++j)                                    \
                    acc[i][j] = __builtin_amdgcn_mfma_f32_16x16x32_bf16(af[i], bfr[j], acc[i][j], 0, 0, 0); \
        }                                                                      \
        __syncthreads();                                                       \
    }

__global__ __launch_bounds__(256, 2) void gemm_u8_kernel(
    const uint16_t* __restrict__ xb,    // bf16 x  [1024][8192] (in ws)
    const uint8_t*  __restrict__ qu8,   // u8      [8192][8192] (in ws)
    const float*    __restrict__ scales,// fp32    [8192][256]
    const float*    __restrict__ t,     // fp32    [1024][16]   (in ws)
    const float*    __restrict__ loraB, // fp32    [8192][16]
    const float*    __restrict__ bias,  // fp32    [8192]
    float*          __restrict__ out)   // fp32    [1024][8192]
{
    __shared__ __align__(16) uint16_t xs[2][BM * BK];   // 2 x 16 KB, swizzled A tiles
    __shared__ __align__(16) uint16_t wt[2][BN * BK];   // 2 x 16 KB, swizzled W tiles

    const int bx    = blockIdx.x;
    const int mtile = bx >> 6;          // proven ordering
    const int ntile = bx & 63;
    const int m0 = mtile * BM;
    const int n0 = ntile * BN;

    const int tid  = threadIdx.x;
    const int wave = tid >> 6;
    const int lane = tid & 63;
    const int wm = wave & 1, wn = wave >> 1;   // 64x64 wave subtile
    const int fr = lane & 15;
    const int quad = lane >> 4;

    // q staging map over the 128x64 tile: thread t -> row (t>>4)+16j, cols (t&15)*4..+3
    const int qrow  = tid >> 4;
    const int qcol4 = (tid & 15) * 4;
    const int qhi   = (tid >> 3) & 1;
    // swizzled wt write position (constant across j since 16j % 8 == 0)
    const int wpos = ((((tid >> 1) & 7) ^ (qrow & 7)) * 8) + (tid & 1) * 4;

    const uint8_t* qbase = qu8 + (size_t)n0 * IN_F + qcol4;   // byte units

    f32x4 acc[4][4];
    const f32x4 z = {0.f, 0.f, 0.f, 0.f};
#pragma unroll
    for (int i = 0; i < 4; ++i)
#pragma unroll
        for (int j = 0; j < 4; ++j) acc[i][j] = z;

    uint32_t qv[2][8];
    float    sc[2][8];

    // ---- prefetch q for kt=0 (covered by the LoRA prologue)
#pragma unroll
    for (int j = 0; j < 8; ++j) {
        const int row = qrow + 16 * j;
        qv[0][j] = *(const uint32_t*)(qbase + (size_t)row * IN_F);
        sc[0][j] = scales[(size_t)(n0 + row) * SCB + qhi];
    }

    // ---- LoRA as one K=32 MFMA step: A'=t[m][r], B'=2*loraB[o][r], zero-padded.
    {
        if (tid < 128) {
            const int row = tid, s = row & 7;
            const float4* tp = (const float4*)(t + (size_t)(m0 + row) * RANK);
            const float4 v0 = tp[0], v1 = tp[1], v2 = tp[2], v3 = tp[3];
            uint32_t vals[8];
            vals[0] = pack_bf16(v0.x, v0.y); vals[1] = pack_bf16(v0.z, v0.w);
            vals[2] = pack_bf16(v1.x, v1.y); vals[3] = pack_bf16(v1.z, v1.w);
            vals[4] = pack_bf16(v2.x, v2.y); vals[5] = pack_bf16(v2.z, v2.w);
            vals[6] = pack_bf16(v3.x, v3.y); vals[7] = pack_bf16(v3.z, v3.w);
            uint32_t* dst = (uint32_t*)(&xs[0][row * BK]);
#pragma unroll
            for (int c = 0; c < 8; ++c) {
                const int p = (c ^ s) * 4;
                if (c < 2) {
                    dst[p + 0] = vals[c * 4 + 0]; dst[p + 1] = vals[c * 4 + 1];
                    dst[p + 2] = vals[c * 4 + 2]; dst[p + 3] = vals[c * 4 + 3];
                } else {
                    dst[p + 0] = 0; dst[p + 1] = 0; dst[p + 2] = 0; dst[p + 3] = 0;
                }
            }
        } else {
            const int row = tid - 128, s = row & 7;
            const float4* bp = (const float4*)(loraB + (size_t)(n0 + row) * RANK);
            const float4 v0 = bp[0], v1 = bp[1], v2 = bp[2], v3 = bp[3];
            uint32_t vals[8];
            vals[0] = pack_bf16(2.f * v0.x, 2.f * v0.y); vals[1] = pack_bf16(2.f * v0.z, 2.f * v0.w);
            vals[2] = pack_bf16(2.f * v1.x, 2.f * v1.y); vals[3] = pack_bf16(2.f * v1.z, 2.f * v1.w);
            vals[4] = pack_bf16(2.f * v2.x, 2.f * v2.y); vals[5] = pack_bf16(2.f * v2.z, 2.f * v2.w);
            vals[6] = pack_bf16(2.f * v3.x, 2.f * v3.y); vals[7] = pack_bf16(2.f * v3.z, 2.f * v3.w);
            uint32_t* dst = (uint32_t*)(&wt[0][row * BK]);
#pragma unroll
            for (int c = 0; c < 8; ++c) {
                const int p = (c ^ s) * 4;
                if (c < 2) {
                    dst[p + 0] = vals[c * 4 + 0]; dst[p + 1] = vals[c * 4 + 1];
                    dst[p + 2] = vals[c * 4 + 2]; dst[p + 3] = vals[c * 4 + 3];
                } else {
                    dst[p + 0] = 0; dst[p + 1] = 0; dst[p + 2] = 0; dst[p + 3] = 0;
                }
            }
        }
        __syncthreads();
        const int pp = (quad ^ (fr & 7)) * 8;    // chunk=quad; quads 2,3 read zeros
        bf16x8 af[4], bfr[4];
#pragma unroll
        for (int i = 0; i < 4; ++i)
            af[i] = *(const bf16x8*)(&xs[0][(wm * 64 + i * 16 + fr) * BK + pp]);
#pragma unroll
        for (int j = 0; j < 4; ++j)
            bfr[j] = *(const bf16x8*)(&wt[0][(wn * 64 + j * 16 + fr) * BK + pp]);
#pragma unroll
        for (int i = 0; i < 4; ++i)
#pragma unroll
            for (int j = 0; j < 4; ++j)
                acc[i][j] = __builtin_amdgcn_mfma_f32_16x16x32_bf16(af[i], bfr[j], acc[i][j], 0, 0, 0);
        __syncthreads();   // LoRA reads done before buffers are restaged
    }

    // xs staging map: lane l stages row wave*32+i*8+(l>>3), global chunk
    // (l&7)^(l>>3), landing at LDS slot l&7 (swizzle realized via global perm).
    const int xrow   = wave * 32 + (lane >> 3);
    const int xchunk = (lane & 7) ^ (lane >> 3);
    const uint16_t* xsrc = xb + (size_t)(m0 + xrow) * IN_F + xchunk * 8;

    // ---- pipeline prologue: stage kt=0 into buffer 0, prefetch q for kt=1
#pragma unroll
    for (int i = 0; i < 4; ++i) {
        __builtin_amdgcn_global_load_lds(
            (const __attribute__((address_space(1))) uint32_t*)(xsrc + (size_t)i * 8 * IN_F),
            (__attribute__((address_space(3))) uint32_t*)(&xs[0][(wave * 32 + i * 8) * BK]),
            16, 0, 0);
    }
#pragma unroll
    for (int j = 0; j < 8; ++j) {
        const float s = sc[0][j];
        const float c = -128.f * s;
        const uint32_t qq = qv[0][j];
        uint2 pk;
        pk.x = pack_bf16(fmaf((float)(qq & 0xffu), s, c),
                         fmaf((float)((qq >> 8) & 0xffu), s, c));
        pk.y = pack_bf16(fmaf((float)((qq >> 16) & 0xffu), s, c),
                         fmaf((float)(qq >> 24), s, c));
        *(uint2*)(&wt[0][(qrow + 16 * j) * BK + wpos]) = pk;
    }
#pragma unroll
    for (int j = 0; j < 8; ++j) {
        const int row = qrow + 16 * j;
        qv[0][j] = *(const uint32_t*)(qbase + (size_t)row * IN_F + 1 * BK);
        sc[0][j] = scales[(size_t)(n0 + row) * SCB + 2 + qhi];
    }
    __syncthreads();

    // ---- main loop, unrolled by 2 for the qv ping-pong
    for (int kt = 0; kt < NK; kt += 2) {
        GEMM_STEP_U(kt,     0, 0, 1);
        GEMM_STEP_U(kt + 1, 1, 1, 0);
    }

    // epilogue: + bias, store fp32 (C/D map: col=lane&15, row=quad*4+reg)
#pragma unroll
    for (int j = 0; j < 4; ++j) {
        const int col = n0 + wn * 64 + j * 16 + fr;
        const float bv = bias[col];
#pragma unroll
        for (int i = 0; i < 4; ++i) {
            const int rbase = m0 + wm * 64 + i * 16 + quad * 4;
#pragma unroll
            for (int r = 0; r < 4; ++r)
                out[(size_t)(rbase + r) * OUT_F + col] = acc[i][j][r] + bv;
        }
    }
}

// ---------------------------------------------------------------------------
// Kernel 3C (legacy int32 fallback): used when ws can't hold qu8.
// ---------------------------------------------------------------------------
#define GEMM_STEP_L(KT, P, CUR, NXT)                                           \
    {                                                                          \
        const int ktn = ((KT) + 2) & (NK - 1);                                 \
        _Pragma("unroll")                                                      \
        for (int j = 0; j < 8; ++j) {                                          \
            const int row = qrow + 16 * j;                                     \
            qv[(P) ^ 1][j] = *(const int4*)(qbase + (size_t)row * IN_F + ktn * BK); \
            sc[(P) ^ 1][j] = scales[(size_t)(n0 + row) * SCB + ktn * 2 + qhi]; \
        }                                                                      \
        const int kta = ((KT) + 1) & (NK - 1);                                 \
        _Pragma("unroll")                                                      \
        for (int i = 0; i < 4; ++i) {                                          \
            __builtin_amdgcn_global_load_lds(                                  \
                (const __attribute__((address_space(1))) uint32_t*)(xsrc + (size_t)kta * BK + (size_t)i * 8 * IN_F), \
                (__attribute__((address_space(3))) uint32_t*)(&xs[NXT][(wave * 32 + i * 8) * BK]), \
                16, 0, 0);                                                     \
        }                                                                      \
        _Pragma("unroll")                                                      \
        for (int j = 0; j < 8; ++j) {                                          \
            const float s = sc[P][j];                                          \
            const float c = -128.f * s;                                        \
            const int4 qq = qv[P][j];                                          \
            uint2 pk;                                                          \
            pk.x = pack_bf16(fmaf((float)qq.x, s, c), fmaf((float)qq.y, s, c)); \
            pk.y = pack_bf16(fmaf((float)qq.z, s, c), fmaf((float)qq.w, s, c)); \
            *(uint2*)(&wt[NXT][(qrow + 16 * j) * BK + wpos]) = pk;             \
        }                                                                      \
        _Pragma("unroll")                                                      \
        for (int kk = 0; kk < BK; kk += 32) {                                  \
            bf16x8 af[4], bfr[4];                                              \
            const int pp = (((kk >> 3) + quad) ^ (fr & 7)) * 8;                \
            _Pragma("unroll")                                                  \
            for (int i = 0; i < 4; ++i)                                        \
                af[i] = *(const bf16x8*)(&xs[CUR][(wm * 64 + i * 16 + fr) * BK + pp]); \
            _Pragma("unroll")                                                  \
            for (int j = 0; j < 4; ++j)                                        \
                bfr[j] = *(const bf16x8*)(&wt[CUR][(wn * 64 + j * 16 + fr) * BK + pp]); \
            _Pragma("unroll")                                                  \
            for (int i = 0; i < 4; ++i)                                        \
                _Pragma("unroll")                                              \
                for (int j = 0; j < 4; ++j)                                    \
                    acc[i][j] = __builtin_amdgcn_mfma_f32_16x16x32_bf16(af[i], bfr[j], acc[i][j], 0, 0, 0); \
        }                                                                      \
        __syncthreads();                                                       \
    }

__global__ __launch_bounds__(256, 2) void gemm_kernel(
    const uint16_t* __restrict__ xb,
    const int*      __restrict__ q,
    const float*    __restrict__ scales,
    const float*    __restrict__ t,
    const float*    __restrict__ loraB,
    const float*    __restrict__ bias,
    float*          __restrict__ out)
{
    __shared__ __align__(16) uint16_t xs[2][BM * BK];
    __shared__ __align__(16) uint16_t wt[2][BN * BK];

    const int bx    = blockIdx.x;
    const int mtile = bx >> 6;
    const int ntile = bx & 63;
    const int m0 = mtile * BM;
    const int n0 = ntile * BN;

    const int tid  = threadIdx.x;
    const int wave = tid >> 6;
    const int lane = tid & 63;
    const int wm = wave & 1, wn = wave >> 1;
    const int fr = lane & 15;
    const int quad = lane >> 4;

    const int qrow  = tid >> 4;
    const int qcol4 = (tid & 15) * 4;
    const int qhi   = (tid >> 3) & 1;
    const int wpos = ((((tid >> 1) & 7) ^ (qrow & 7)) * 8) + (tid & 1) * 4;

    const int* qbase = q + (size_t)n0 * IN_F + qcol4;

    f32x4 acc[4][4];
    const f32x4 z = {0.f, 0.f, 0.f, 0.f};
#pragma unroll
    for (int i = 0; i < 4; ++i)
#pragma unroll
        for (int j = 0; j < 4; ++j) acc[i][j] = z;

    int4  qv[2][8];
    float sc[2][8];

#pragma unroll
    for (int j = 0; j < 8; ++j) {
        const int row = qrow + 16 * j;
        qv[0][j] = *(const int4*)(qbase + (size_t)row * IN_F);
        sc[0][j] = scales[(size_t)(n0 + row) * SCB + qhi];
    }

    {
        if (tid < 128) {
            const int row = tid, s = row & 7;
            const float4* tp = (const float4*)(t + (size_t)(m0 + row) * RANK);
            const float4 v0 = tp[0], v1 = tp[1], v2 = tp[2], v3 = tp[3];
            uint32_t vals[8];
            vals[0] = pack_bf16(v0.x, v0.y); vals[1] = pack_bf16(v0.z, v0.w);
            vals[2] = pack_bf16(v1.x, v1.y); vals[3] = pack_bf16(v1.z, v1.w);
            vals[4] = pack_bf16(v2.x, v2.y); vals[5] = pack_bf16(v2.z, v2.w);
            vals[6] = pack_bf16(v3.x, v3.y); vals[7] = pack_bf16(v3.z, v3.w);
            uint32_t* dst = (uint32_t*)(&xs[0][row * BK]);
#pragma unroll
            for (int c = 0; c < 8; ++c) {
                const int p = (c ^ s) * 4;
                if (c < 2) {
                    dst[p + 0] = vals[c * 4 + 0]; dst[p + 1] = vals[c * 4 + 1];
                    dst[p + 2] = vals[c * 4 + 2]; dst[p + 3] = vals[c * 4 + 3];
                } else {
                    dst[p + 0] = 0; dst[p + 1] = 0; dst[p + 2] = 0; dst[p + 3] = 0;
                }
            }
        } else {
            const int row = tid - 128, s = row & 7;
            const float4* bp = (const float4*)(loraB + (size_t)(n0 + row) * RANK);
            const float4 v0 = bp[0], v1 = bp[1], v2 = bp[2], v3 = bp[3];
            uint32_t vals[8];
            vals[0] = pack_bf16(2.f * v0.x, 2.f * v0.y); vals[1] = pack_bf16(2.f * v0.z, 2.f * v0.w);
            vals[2] = pack_bf16(2.f * v1.x, 2.f * v1.y); vals[3] = pack_bf16(2.f * v1.z, 2.f * v1.w);
            vals[4] = pack_bf16(2.f * v2.x, 2.f * v2.y); vals[5] = pack_bf16(2.f * v2.z, 2.f * v2.w);
            vals[6] = pack_bf16(2.f * v3.x, 2.f * v3.y); vals[7] = pack_bf16(2.f * v3.z, 2.f * v3.w);
            uint32_t* dst = (uint32_t*)(&wt[0][row * BK]);
#pragma unroll
            for (int c = 0; c < 8; ++c) {
                const int p = (c ^ s) * 4;
                if (c < 2) {
                    dst[p + 0] = vals[c * 4 + 0]; dst[p + 1] = vals[c * 4 + 1];
                    dst[p + 2] = vals[c * 4 + 2]; dst[p + 3] = vals[c * 4 + 3];
                } else {
                    dst[p + 0] = 0; dst[p + 1] = 0; dst[p + 2] = 0; dst[p + 3] = 0;
                }
            }
        }
        __syncthreads();
        const int pp = (quad ^ (fr & 7)) * 8;
        bf16x8 af[4], bfr[4];
#pragma unroll
        for (int i = 0; i < 4; ++i)
            af[i] = *(const bf16x8*)(&xs[0][(wm * 64 + i * 16 + fr) * BK + pp]);
#pragma unroll
        for (int j = 0; j < 4; ++j)
            bfr[j] = *(const bf16x8*)(&wt[0][(wn * 64 + j * 16 + fr) * BK + pp]);
#pragma unroll
        for (int i = 0; i < 4; ++i)
#pragma unroll
            for (int j = 0; j < 4; ++j)
                acc[i][j] = __builtin_amdgcn_mfma_f32_16x16x32_bf16(af[i], bfr[j], acc[i][j], 0, 0, 0);
        __syncthreads();
    }

    const int xrow   = wave * 32 + (lane >> 3);
    const int xchunk = (lane & 7) ^ (lane >> 3);
    const uint16_t* xsrc = xb + (size_t)(m0 + xrow) * IN_F + xchunk * 8;

#pragma unroll
    for (int i = 0; i < 4; ++i) {
        __builtin_amdgcn_global_load_lds(
            (const __attribute__((address_space(1))) uint32_t*)(xsrc + (size_t)i * 8 * IN_F),
            (__attribute__((address_space(3))) uint32_t*)(&xs[0][(wave * 32 + i * 8) * BK]),
            16, 0, 0);
    }
#pragma unroll
    for (int j = 0; j < 8; ++j) {
        const float s = sc[0][j];
        const float c = -128.f * s;
        const int4 qq = qv[0][j];
        uint2 pk;
        pk.x = pack_bf16(fmaf((float)qq.x, s, c), fmaf((float)qq.y, s, c));
        pk.y = pack_bf16(fmaf((float)qq.z, s, c), fmaf((float)qq.w, s, c));
        *(uint2*)(&wt[0][(qrow + 16 * j) * BK + wpos]) = pk;
    }
#pragma unroll
    for (int j = 0; j < 8; ++j) {
        const int row = qrow + 16 * j;
        qv[0][j] = *(const int4*)(qbase + (size_t)row * IN_F + 1 * BK);
        sc[0][j] = scales[(size_t)(n0 + row) * SCB + 2 + qhi];
    }
    __syncthreads();

    for (int kt = 0; kt < NK; kt += 2) {
        GEMM_STEP_L(kt,     0, 0, 1);
        GEMM_STEP_L(kt + 1, 1, 1, 0);
    }

#pragma unroll
    for (int j = 0; j < 4; ++j) {
        const int col = n0 + wn * 64 + j * 16 + fr;
        const float bv = bias[col];
#pragma unroll
        for (int i = 0; i < 4; ++i) {
            const int rbase = m0 + wm * 64 + i * 16 + quad * 4;
#pragma unroll
            for (int r = 0; r < 4; ++r)
                out[(size_t)(rbase + r) * OUT_F + col] = acc[i][j][r] + bv;
        }
    }
}

extern "C" void kernel_launch(void* const* d_in, const int* in_sizes, int n_in,
                              void* d_out, int out_size, void* d_ws, size_t ws_size,
                              hipStream_t stream) {
    const float* x      = (const float*)d_in[0];
    const int*   q      = (const int*)d_in[1];
    const float* scales = (const float*)d_in[2];
    const float* lora_A = (const float*)d_in[3];
    const float* lora_B = (const float*)d_in[4];
    const float* bias   = (const float*)d_in[5];
    float* out = (float*)d_out;

    // ws layout: [0,16MB) xb bf16[1024][8192]; t fp32[1024][16]; then qu8
    const size_t xb_bytes = (size_t)M_TOT * IN_F * sizeof(uint16_t);   // 16 MB
    const size_t t_bytes  = (size_t)M_TOT * RANK * sizeof(float);      // 64 KB
    const size_t q8_off   = xb_bytes + t_bytes;                        // 16B-aligned
    const size_t q8_bytes = (size_t)OUT_F * IN_F;                      // 64 MB

    uint16_t* xb = (uint16_t*)d_ws;
    float*    t  = (float*)((char*)d_ws + xb_bytes);

    if (ws_size >= q8_off + q8_bytes) {
        uint8_t* qu8 = (uint8_t*)d_ws + q8_off;
        prep_kernel<<<2048, 256, 0, stream>>>(x, q, (uint2*)xb, (uint32_t*)qu8, t);
        lora_t_kernel<<<1024, 256, 0, stream>>>(xb, lora_A, t);
        gemm_u8_kernel<<<(M_TOT / BM) * (OUT_F / BN), 256, 0, stream>>>(
            xb, qu8, scales, t, lora_B, bias, out);
    } else {
        convert_kernel<<<M_TOT, 256, 0, stream>>>(x, (uint2*)xb, t);
        lora_t_kernel<<<1024, 256, 0, stream>>>(xb, lora_A, t);
        gemm_kernel<<<(M_TOT / BM) * (OUT_F / BN), 256, 0, stream>>>(
            xb, q, scales, t, lora_B, bias, out);
    }
}